// Round 1
// baseline (152.744 us; speedup 1.0000x reference)
//
#include <hip/hip_runtime.h>
#include <cstdint>
#include <cstddef>

// Problem constants: B=1024, T=12, D=512
#define Bsz 1024
#define Tsz 12
#define Dsz 512

#define BM 128           // j tile (rows of P)
#define BN 128           // i tile (rows of X)
#define BKg 32           // K-chunk per stage
#define NIB (Bsz / BN)   // 8 i-tiles per column

typedef _Float16 h4    __attribute__((ext_vector_type(4)));
typedef _Float16 f16x8 __attribute__((ext_vector_type(8)));
typedef float    f32x4 __attribute__((ext_vector_type(4)));

// fp32 -> f16 hi/lo split (hi = rne(x), lo = rne(x - hi)); hi*hi / hi*lo /
// lo*hi accumulate in fp32 inside the MFMA; dropped lo*lo ~2^-22 relative.
__device__ __forceinline__ void cvt_store(const float4 v, _Float16* hp, _Float16* lp) {
    _Float16 hx = (_Float16)v.x, hy = (_Float16)v.y,
             hz = (_Float16)v.z, hw = (_Float16)v.w;
    h4 hh = {hx, hy, hz, hw};
    h4 ll = {(_Float16)(v.x - (float)hx), (_Float16)(v.y - (float)hy),
             (_Float16)(v.z - (float)hz), (_Float16)(v.w - (float)hw)};
    *(h4*)hp = hh;
    *(h4*)lp = ll;
}

// async global->LDS, 16B per lane; LDS dest is wave-uniform base + lane*16.
__device__ __forceinline__ void gload_lds16(const _Float16* g, _Float16* l) {
    __builtin_amdgcn_global_load_lds(
        (const __attribute__((address_space(1))) void*)g,
        (__attribute__((address_space(3))) void*)l, 16, 0, 0);
}

// One-time fp32 -> f16 hi/lo conversion, layout transposed to [T][B][D] so a
// GEMM tile's rows are contiguous per t. Replaces the per-block (16x / 8x
// redundant) VALU conversion that made the old gemm VALU-bound. Also zeroes out.
__global__ __launch_bounds__(256) void convert_kernel(
    const float* __restrict__ P, const float* __restrict__ X,
    _Float16* __restrict__ Ph, _Float16* __restrict__ Pl,
    _Float16* __restrict__ Xh, _Float16* __restrict__ Xl,
    float* __restrict__ out)
{
    const int gtid = blockIdx.x * 256 + threadIdx.x;
    if (gtid < 2) out[gtid] = 0.0f;
    const int nf4 = Bsz * Tsz * (Dsz / 4);       // 1,572,864 float4 per tensor
    for (int f = gtid; f < nf4; f += gridDim.x * 256) {
        const int row = f >> 7;                  // / (D/4 = 128)
        const int d4  = f & 127;
        const int b   = row / Tsz;
        const int t   = row - b * Tsz;
        const size_t oi = ((size_t)t * Bsz + b) * Dsz + (size_t)d4 * 4;
        const float4 pv = ((const float4*)P)[f];
        cvt_store(pv, &Ph[oi], &Pl[oi]);
        const float4 xv = ((const float4*)X)[f];
        cvt_store(xv, &Xh[oi], &Xl[oi]);
    }
}

// Fused GEMM + tile softmax-partials. dots[t,i,j] = <P[j,t,:], X[i,t,:]>.
// 128x128 tile, 4 waves in 2x2 (wave tile 64x64): 48 MFMA : 16 ds_read_b128
// per wave-K-step. Staging via global_load_lds dwordx4 (no VALU), with XOR
// granule swizzle g' = g ^ ((row>>1)&3) baked into the GLOBAL source address
// (linear LDS dest) and applied again on the ds_read side -> <=2-way banks.
__global__ __launch_bounds__(256, 3) void gemm_fused_kernel(
    const _Float16* __restrict__ Phg, const _Float16* __restrict__ Plg,
    const _Float16* __restrict__ Xhg, const _Float16* __restrict__ Xlg,
    float* __restrict__ pm,        // [Tsz*Bsz*NIB] tile max
    float* __restrict__ ps,        // [Tsz*Bsz*NIB] tile sum exp
    int*   __restrict__ pa,        // [Tsz*Bsz*NIB] tile argmax (global i)
    float* __restrict__ diag)      // [Tsz*Bsz]
{
    const int t  = blockIdx.z;
    const int bx = blockIdx.x;
    const int ib = bx * BN;             // i tile (n-dim)
    const int jb = blockIdx.y * BM;     // j tile (m-dim)
    const int tid  = threadIdx.x;
    const int lane = tid & 63;
    const int w    = tid >> 6;          // wave 0..3
    const int jw   = (w >> 1) * 64;     // wave j-offset
    const int iw   = (w & 1) * 64;      // wave i-offset
    const int ml   = lane & 15;
    const int quad = lane >> 4;

    __shared__ _Float16 Lds[4][BM][BKg];   // 0=Ph 1=Pl 2=Xh 3=Xl, 8KB each
    __shared__ float sm_m[BM][2];
    __shared__ float sm_s[BM][2];
    __shared__ int   sm_a[BM][2];

    f32x4 acc[4][4];
#pragma unroll
    for (int r = 0; r < 4; ++r)
#pragma unroll
        for (int c = 0; c < 4; ++c) acc[r][c] = (f32x4){0.f, 0.f, 0.f, 0.f};

    // ---- staging setup: wave w owns tile w; 8 instrs stage 128 rows x 32 k ----
    const _Float16* tb = (w == 0) ? Phg : (w == 1) ? Plg : (w == 2) ? Xhg : Xlg;
    const int rb = (w < 2) ? jb : ib;
    // lane l -> row = h*16 + (l>>2), granule position g' = l&3; source granule
    // g = g' ^ ((row>>1)&3) = (l&3) ^ ((l>>3)&3)  (h*16 doesn't touch bits 1..2)
    const _Float16* gbase = tb + ((size_t)t * Bsz + rb) * Dsz
                          + (size_t)(lane >> 2) * Dsz
                          + (((lane & 3) ^ ((lane >> 3) & 3)) << 3);

    // ds_read swizzle: row = 16*m + ml -> (row>>1)&3 = (ml>>1)&3
    const int fsw = ((quad ^ ((ml >> 1) & 3)) << 3);

    for (int k0 = 0; k0 < Dsz; k0 += BKg) {
#pragma unroll
        for (int h = 0; h < 8; ++h)
            gload_lds16(gbase + (size_t)(h * 16) * Dsz + k0, &Lds[w][h * 16][0]);
        __syncthreads();

        // ---- fragments (swizzled reads, <=2-way bank) ----
        f16x8 ah[4], al[4], bh[4], bl[4];
#pragma unroll
        for (int r = 0; r < 4; ++r) {
            ah[r] = *(const f16x8*)&Lds[0][jw + r * 16 + ml][fsw];
            al[r] = *(const f16x8*)&Lds[1][jw + r * 16 + ml][fsw];
        }
#pragma unroll
        for (int c = 0; c < 4; ++c) {
            bh[c] = *(const f16x8*)&Lds[2][iw + c * 16 + ml][fsw];
            bl[c] = *(const f16x8*)&Lds[3][iw + c * 16 + ml][fsw];
        }

        // ---- MFMA: hi*hi + hi*lo + lo*hi (same order as before -> same bits) ----
#pragma unroll
        for (int r = 0; r < 4; ++r)
#pragma unroll
            for (int c = 0; c < 4; ++c) {
                acc[r][c] = __builtin_amdgcn_mfma_f32_16x16x32_f16(ah[r], bh[c], acc[r][c], 0, 0, 0);
                acc[r][c] = __builtin_amdgcn_mfma_f32_16x16x32_f16(ah[r], bl[c], acc[r][c], 0, 0, 0);
                acc[r][c] = __builtin_amdgcn_mfma_f32_16x16x32_f16(al[r], bh[c], acc[r][c], 0, 0, 0);
            }
        __syncthreads();
    }

    // ---- diag extraction (global index test; epilogue-only) ----
#pragma unroll
    for (int r = 0; r < 4; ++r)
#pragma unroll
        for (int v = 0; v < 4; ++v) {
            const int jg = jb + jw + r * 16 + quad * 4 + v;
#pragma unroll
            for (int c = 0; c < 4; ++c) {
                const int ig = ib + iw + c * 16 + ml;
                if (ig == jg) diag[(size_t)t * Bsz + jg] = acc[r][c][v];
            }
        }

    // ---- per-row (j) partial over this wave's 64-i slice ----
    // acc[r][c][v] sits at row j = jw+r*16+quad*4+v, col i = iw+c*16+ml.
#pragma unroll
    for (int r = 0; r < 4; ++r)
#pragma unroll
        for (int v = 0; v < 4; ++v) {
            float m = acc[r][0][v];
            int   ai = iw + ml;
#pragma unroll
            for (int c = 1; c < 4; ++c) {
                const float val = acc[r][c][v];
                if (val > m) { m = val; ai = iw + c * 16 + ml; }   // ascending c -> ties keep smaller i
            }
#pragma unroll
            for (int off = 1; off < 16; off <<= 1) {
                const float om = __shfl_xor(m, off);
                const int   oi = __shfl_xor(ai, off);
                if (om > m || (om == m && oi < ai)) { m = om; ai = oi; }
            }
            float s = 0.0f;
#pragma unroll
            for (int c = 0; c < 4; ++c) s += __expf(acc[r][c][v] - m);
#pragma unroll
            for (int off = 1; off < 16; off <<= 1) s += __shfl_xor(s, off);

            if (ml == 0) {
                const int row = jw + r * 16 + quad * 4 + v;
                sm_m[row][iw >> 6] = m;
                sm_s[row][iw >> 6] = s;
                sm_a[row][iw >> 6] = ib + ai;   // global i
            }
        }
    __syncthreads();

    // ---- combine the two i-halves, write tile partials ----
    if (tid < BM) {
        const int row = tid;
        const float m0 = sm_m[row][0], m1 = sm_m[row][1];
        const float s0 = sm_s[row][0], s1 = sm_s[row][1];
        float M; int A;
        if (m1 > m0) { M = m1; A = sm_a[row][1]; }   // tie -> half 0 (smaller i)
        else         { M = m0; A = sm_a[row][0]; }
        const float S = s0 * __expf(m0 - M) + s1 * __expf(m1 - M);
        const size_t slot = ((size_t)t * Bsz + (jb + row)) * NIB + bx;
        pm[slot] = M;
        ps[slot] = S;
        pa[slot] = A;
    }
}

// One thread per (t,j) column: merge NIB tile partials, 48 block atomics.
__global__ __launch_bounds__(256) void combine_kernel(
    const float* __restrict__ pm,
    const float* __restrict__ ps,
    const int*   __restrict__ pa,
    const float* __restrict__ diag,
    float* __restrict__ out)
{
    const int col = blockIdx.x * 256 + threadIdx.x;   // 0..Tsz*Bsz-1
    const int j = col & (Bsz - 1);

    const size_t base = (size_t)col * NIB;
    float M = pm[base]; int A = pa[base];
#pragma unroll
    for (int b = 1; b < NIB; ++b) {
        const float mb = pm[base + b];
        if (mb > M) { M = mb; A = pa[base + b]; }   // tie -> earlier b = smaller i
    }
    float S = 0.0f;
#pragma unroll
    for (int b = 0; b < NIB; ++b) S += ps[base + b] * __expf(pm[base + b] - M);

    const float lse = M + logf(S);
    float sl = lse - diag[col];
    float sc = (A == j) ? 1.0f : 0.0f;

#pragma unroll
    for (int off = 1; off < 64; off <<= 1) {
        sl += __shfl_xor(sl, off);
        sc += __shfl_xor(sc, off);
    }

    __shared__ float wl[4], wc[4];
    const int w = threadIdx.x >> 6;
    if ((threadIdx.x & 63) == 0) { wl[w] = sl; wc[w] = sc; }
    __syncthreads();
    if (threadIdx.x == 0) {
        const float inv = 1.0f / (float)(Bsz * Tsz);
        atomicAdd(&out[0], (wl[0] + wl[1] + wl[2] + wl[3]) * inv);  // -loss
        atomicAdd(&out[1], (wc[0] + wc[1] + wc[2] + wc[3]) * inv);  // accuracy
    }
}

extern "C" void kernel_launch(void* const* d_in, const int* in_sizes, int n_in,
                              void* d_out, int out_size, void* d_ws, size_t ws_size,
                              hipStream_t stream) {
    const float* P = (const float*)d_in[0];  // predictions [B,T,D]
    const float* X = (const float*)d_in[1];  // x_future_encoded [B,T,D]
    float* out = (float*)d_out;

    const size_t ncol  = (size_t)Bsz * Tsz;          // 12288
    const size_t nslot = ncol * NIB;                 // 98304
    const size_t nel   = (size_t)Bsz * Tsz * Dsz;    // 6,291,456

    float* pm   = (float*)d_ws;
    float* ps   = pm + nslot;
    int*   pa   = (int*)(ps + nslot);
    float* diag = (float*)(pa + nslot);
    _Float16* Ph = (_Float16*)(diag + ncol);         // byte offset 1,228,800 (16B aligned)
    _Float16* Pl = Ph + nel;
    _Float16* Xh = Pl + nel;
    _Float16* Xl = Xh + nel;                          // total ws ~51.6 MB

    convert_kernel<<<dim3(2048), dim3(256), 0, stream>>>(P, X, Ph, Pl, Xh, Xl, out);

    gemm_fused_kernel<<<dim3(NIB, Bsz / BM, Tsz), dim3(256), 0, stream>>>(
        Ph, Pl, Xh, Xl, pm, ps, pa, diag);

    combine_kernel<<<dim3((int)(ncol / 256)), dim3(256), 0, stream>>>(
        pm, ps, pa, diag, out);
}